// Round 4
// baseline (491.233 us; speedup 1.0000x reference)
//
#include <hip/hip_runtime.h>

#define NN 100000
#define EE 3200000
#define FIN 512
#define HH 16
#define CC 40

#define SHIFT 9
#define BNODES 512                       // nodes per bucket
#define NB 196                           // ceil(NN/BNODES)
#define CAP 20480                        // per-bucket slot capacity (mean 16384, +32 sigma)
#define CH 2048                          // edges per binning chunk (8/thread in regs)
#define TC ((EE + CH - 1) / CH)          // 1563 chunks
#define GB ((NN * 4 + 255) / 256)        // 1563 blocks for quad-per-node kernels
#define GB2 ((NN + 63) / 64)             // 1563 gemm blocks (64 nodes each)

// bf16 helpers (manual RTNE; values here are finite and well-scaled)
__device__ __forceinline__ float bf2f(unsigned short u) {
    return __uint_as_float(((unsigned)u) << 16);
}
__device__ __forceinline__ unsigned short f2bf(float f) {
    unsigned b = __float_as_uint(f);
    return (unsigned short)((b + 0x7FFF + ((b >> 16) & 1)) >> 16);
}

// ---------------- bin edges into fixed-capacity buckets (packed u32) ----------
// Single pass over edge_index; 8 edges/thread held in REGISTERS (static-index
// unroll) between histogram and placement phases — no LDS stash, LDS = 2.4 KB.
// word = (dst_local << 17) | src   (src < 2^17, dst_local < 512)
__global__ void k_bin(const int* __restrict__ ei, int* __restrict__ head,
                      unsigned* __restrict__ pairs) {
    __shared__ int h[NB];
    __shared__ int gbase[NB];
    __shared__ int lhead[NB];
    __shared__ int is64_s;
    int t = threadIdx.x;
    // inline dtype detect: int64 layout => high words (odd int32 slots) all zero
    if (t < 64) {
        int nz = (ei[2 * t + 1] != 0) ? 1 : 0;
        unsigned long long m = __ballot(nz);
        if (t == 0) is64_s = (m == 0ULL) ? 1 : 0;
    }
    for (int i = t; i < NB; i += 256) { h[i] = 0; lhead[i] = 0; }
    __syncthreads();
    int is64 = is64_s;
    int e0 = blockIdx.x * CH;
    unsigned es[8], ed[8];
    // phase A: read edges ONCE into registers, histogram dst buckets
#pragma unroll
    for (int j = 0; j < 8; ++j) {
        int e = e0 + j * 256 + t;
        if (e < EE) {
            es[j] = (unsigned)(is64 ? ei[2 * e] : ei[e]);
            ed[j] = (unsigned)(is64 ? ei[2 * (EE + e)] : ei[EE + e]);
            atomicAdd(&h[ed[j] >> SHIFT], 1);
        }
    }
    __syncthreads();
    // one global reservation per (block,bucket): block-private contiguous runs
    for (int i = t; i < NB; i += 256)
        gbase[i] = h[i] ? atomicAdd(&head[i], h[i]) : 0;
    __syncthreads();
    // phase B: place from registers
#pragma unroll
    for (int j = 0; j < 8; ++j) {
        int e = e0 + j * 256 + t;
        if (e < EE) {
            int b = (int)(ed[j] >> SHIFT);
            int p = gbase[b] + atomicAdd(&lhead[b], 1);
            pairs[(size_t)b * CAP + p] = ((ed[j] & (BNODES - 1)) << 17) | es[j];
        }
    }
}

// ------- fused: blocks [0,NB) build CSR; blocks [NB,NB+GB2) compute g1f -------
// R3 gemm was latency/request-rate bound: lane=node gave 2048-B-strided loads
// (64 lines/instr) with VGPR=20 (1 load in flight). New mapping: x is staged
// through LDS in K-chunks (reg-staged, double-buffered; global loads are 8
// nodes x 128 B contiguous per instr), LDS tile XOR-swizzled ((row&7)<<4, G4)
// for conflict-lite strided reads. Wave w owns feature quad 4w..4w+3 so the
// W1 operand stays wave-uniform -> s_load; each thread ends with final acc[4]
// (no reduction). Output UNSCALED f32; k_scale applies dinv (bf16 round once).
__global__ void __launch_bounds__(256) k_buildgemm(
        const unsigned* __restrict__ pairs, const int* __restrict__ head,
        int* __restrict__ ptr, int* __restrict__ pend,
        float* __restrict__ dinv, int* __restrict__ srcs,
        const float* __restrict__ x, const float* __restrict__ W1,
        float* __restrict__ g1f) {
    __shared__ float xs[2][64][32];  // 16 KB double-buffered x tile
    int t = threadIdx.x;
    if (blockIdx.x < NB) {
        // ---------------- build path (LDS overlay on xs) ----------------
        int* h   = (int*)xs;                // [BNODES]
        int* lex = (int*)xs + BNODES;       // [BNODES]
        int* wsm = (int*)xs + 2 * BNODES;   // [4]
        int b = blockIdx.x, lane = t & 63, wid = t >> 6;
        int node0 = b << SHIFT;
        int p0 = b * CAP;
        int cnt = head[b];
        for (int i = t; i < BNODES; i += 256) h[i] = 0;
        __syncthreads();
        for (int p = t; p < cnt; p += 256) atomicAdd(&h[pairs[p0 + p] >> 17], 1);
        __syncthreads();
        // exclusive scan over 512 counts: thread t owns elements 2t, 2t+1
        int a0 = h[2 * t], a1 = h[2 * t + 1];
        int s = a0 + a1;
        int v = s;
#pragma unroll
        for (int off = 1; off < 64; off <<= 1) {
            int u = __shfl_up(v, off);
            if (lane >= off) v += u;
        }
        if (lane == 63) wsm[wid] = v;
        __syncthreads();
        int add = 0;
        for (int w = 0; w < wid; ++w) add += wsm[w];
        int incl = v + add;
        int e0 = incl - s;
        lex[2 * t] = e0;
        lex[2 * t + 1] = e0 + a0;
        __syncthreads();
        for (int i = t; i < BNODES; i += 256) {
            int n = node0 + i;
            if (n < NN) {
                int st = p0 + lex[i];
                ptr[n] = st;
                pend[n] = st + h[i];
                dinv[n] = rsqrtf((float)(h[i] + 1));  // +1 self loop
            }
        }
        __syncthreads();
        for (int p = t; p < cnt; p += 256) {
            unsigned w = pairs[p0 + p];
            int pos = p0 + atomicAdd(&lex[w >> 17], 1);
            srcs[pos] = (int)(w & 0x1FFFF);
        }
    } else {
        // ------------- gemm path: g1f = x @ W1 (f32, unscaled) -----------
        int w = __builtin_amdgcn_readfirstlane(t >> 6);  // wave id = feature quad
        int lane = t & 63;                               // node within block
        int ln7 = lane & 7;
        int base = (blockIdx.x - NB) * 64;
        // staging geometry: instr slot J=w*2+j covers rows J*8..J*8+7;
        // lane l -> row J*8+(l>>3), k-slot l&7 (128 B contiguous per row)
        int r0 = w * 16 + (lane >> 3);
        int r1 = r0 + 8;
        const float* src0 = x + (size_t)min(base + r0, NN - 1) * FIN + ln7 * 4;
        const float* src1 = x + (size_t)min(base + r1, NN - 1) * FIN + ln7 * 4;
        int c0 = (ln7 ^ (r0 & 7)) * 4;  // XOR-swizzled LDS column (write side)
        int c1 = (ln7 ^ (r1 & 7)) * 4;
        const float* wq = W1 + w * 4;   // uniform feature-quad base -> s_load
        float4 acc = make_float4(0.f, 0.f, 0.f, 0.f);
        // prologue: stage chunk 0
        {
            float4 v0 = *(const float4*)(src0);
            float4 v1 = *(const float4*)(src1);
            *(float4*)&xs[0][r0][c0] = v0;
            *(float4*)&xs[0][r1][c1] = v1;
        }
        __syncthreads();
#pragma unroll 4
        for (int ch = 0; ch < 16; ++ch) {
            int cb = ch & 1;
            // issue next chunk's global loads (latency hides under compute)
            float4 n0, n1;
            if (ch < 15) {
                n0 = *(const float4*)(src0 + (ch + 1) * 32);
                n1 = *(const float4*)(src1 + (ch + 1) * 32);
            }
            // compute current chunk: 32 k x 4 features
#pragma unroll
            for (int s = 0; s < 8; ++s) {
                float4 xv = *(const float4*)&xs[cb][lane][(s ^ ln7) * 4];
                const float* wr = wq + (ch * 32 + s * 4) * HH;  // uniform
                acc.x = fmaf(xv.x, wr[0], acc.x);
                acc.y = fmaf(xv.x, wr[1], acc.y);
                acc.z = fmaf(xv.x, wr[2], acc.z);
                acc.w = fmaf(xv.x, wr[3], acc.w);
                acc.x = fmaf(xv.y, wr[HH + 0], acc.x);
                acc.y = fmaf(xv.y, wr[HH + 1], acc.y);
                acc.z = fmaf(xv.y, wr[HH + 2], acc.z);
                acc.w = fmaf(xv.y, wr[HH + 3], acc.w);
                acc.x = fmaf(xv.z, wr[2 * HH + 0], acc.x);
                acc.y = fmaf(xv.z, wr[2 * HH + 1], acc.y);
                acc.z = fmaf(xv.z, wr[2 * HH + 2], acc.z);
                acc.w = fmaf(xv.z, wr[2 * HH + 3], acc.w);
                acc.x = fmaf(xv.w, wr[3 * HH + 0], acc.x);
                acc.y = fmaf(xv.w, wr[3 * HH + 1], acc.y);
                acc.z = fmaf(xv.w, wr[3 * HH + 2], acc.z);
                acc.w = fmaf(xv.w, wr[3 * HH + 3], acc.w);
            }
            // write next chunk to the other buffer (no hazard: different buf),
            // single barrier per chunk publishes it for the next iteration
            if (ch < 15) {
                *(float4*)&xs[cb ^ 1][r0][c0] = n0;
                *(float4*)&xs[cb ^ 1][r1][c1] = n1;
            }
            __syncthreads();
        }
        int node = base + lane;
        if (node < NN)
            reinterpret_cast<float4*>(g1f)[node * 4 + w] = acc;
    }
}

// ---- tiny pass: g1 = bf16(g1f * dinv) — single bf16 rounding, same as R1 -----
__global__ void k_scale(const float* __restrict__ g1f, const float* __restrict__ dinv,
                        unsigned short* __restrict__ g1) {
    int gt = blockIdx.x * 256 + threadIdx.x;
    int node = gt >> 2, q = gt & 3;
    if (node >= NN) return;
    float di = dinv[node];
    float4 v = reinterpret_cast<const float4*>(g1f)[node * 4 + q];
    ushort4 o;
    o.x = f2bf(v.x * di);
    o.y = f2bf(v.y * di);
    o.z = f2bf(v.z * di);
    o.w = f2bf(v.w * di);
    reinterpret_cast<ushort4*>(g1)[node * 4 + q] = o;
}

// ---------------- agg1: CSR gather (bf16), relu epilogue -> g2h (bf16) --------
__global__ void k_agg1(const unsigned short* __restrict__ g1, const int* __restrict__ ptr,
                       const int* __restrict__ pend, const int* __restrict__ srcs,
                       const float* __restrict__ dinv, const float* __restrict__ b1,
                       unsigned short* __restrict__ g2h) {
    int gt = blockIdx.x * blockDim.x + threadIdx.x;
    int node = gt >> 2, q = gt & 3;
    if (node >= NN) return;
    const ushort4* G = reinterpret_cast<const ushort4*>(g1);
    ushort4 sv = G[node * 4 + q];  // self term
    float ax = bf2f(sv.x), ay = bf2f(sv.y), az = bf2f(sv.z), aw = bf2f(sv.w);
    float bx = 0.f, by = 0.f, bz = 0.f, bw = 0.f;
    float cx = 0.f, cy = 0.f, cz = 0.f, cw = 0.f;
    float dx = 0.f, dy = 0.f, dz = 0.f, dw = 0.f;
    int e = ptr[node], e1 = pend[node];
    for (; e + 3 < e1; e += 4) {
        int s0 = srcs[e], s1 = srcs[e + 1], s2 = srcs[e + 2], s3 = srcs[e + 3];
        ushort4 v0 = G[s0 * 4 + q];
        ushort4 v1 = G[s1 * 4 + q];
        ushort4 v2 = G[s2 * 4 + q];
        ushort4 v3 = G[s3 * 4 + q];
        ax += bf2f(v0.x); ay += bf2f(v0.y); az += bf2f(v0.z); aw += bf2f(v0.w);
        bx += bf2f(v1.x); by += bf2f(v1.y); bz += bf2f(v1.z); bw += bf2f(v1.w);
        cx += bf2f(v2.x); cy += bf2f(v2.y); cz += bf2f(v2.z); cw += bf2f(v2.w);
        dx += bf2f(v3.x); dy += bf2f(v3.y); dz += bf2f(v3.z); dw += bf2f(v3.w);
    }
    for (; e < e1; ++e) {
        ushort4 v = G[srcs[e] * 4 + q];
        ax += bf2f(v.x); ay += bf2f(v.y); az += bf2f(v.z); aw += bf2f(v.w);
    }
    ax += bx + cx + dx;
    ay += by + cy + dy;
    az += bz + cz + dz;
    aw += bw + cw + dw;
    float di = dinv[node];
    const float4 bb = reinterpret_cast<const float4*>(b1)[q];
    ushort4 r;
    r.x = f2bf(fmaxf(fmaf(di, ax, bb.x), 0.f) * di);
    r.y = f2bf(fmaxf(fmaf(di, ay, bb.y), 0.f) * di);
    r.z = f2bf(fmaxf(fmaf(di, az, bb.z), 0.f) * di);
    r.w = f2bf(fmaxf(fmaf(di, aw, bb.w), 0.f) * di);
    reinterpret_cast<ushort4*>(g2h)[node * 4 + q] = r;
}

// ------ fused agg2 + out: CSR gather -> W2 partials -> quad butterfly ---------
// ------   -> bias/scale -> log_softmax -> direct write of final output --------
__global__ void __launch_bounds__(256) k_agg2out(
        const unsigned short* __restrict__ g2h, const int* __restrict__ ptr,
        const int* __restrict__ pend, const int* __restrict__ srcs,
        const float* __restrict__ dinv, const float* __restrict__ W2,
        const float* __restrict__ b2, float* __restrict__ out) {
    __shared__ float w2s[HH * 41];  // stride 41 breaks 4-way bank conflict (160%32==0)
    __shared__ float b2s[CC];
    int t = threadIdx.x;
    for (int i = t; i < HH * CC; i += 256) w2s[(i / CC) * 41 + (i % CC)] = W2[i];
    if (t < CC) b2s[t] = b2[t];
    __syncthreads();
    int gt = blockIdx.x * blockDim.x + t;
    int node = gt >> 2, q = gt & 3;
    if (node >= NN) return;
    const ushort4* G = reinterpret_cast<const ushort4*>(g2h);
    ushort4 sv = G[node * 4 + q];  // self term
    float ax = bf2f(sv.x), ay = bf2f(sv.y), az = bf2f(sv.z), aw = bf2f(sv.w);
    float bx = 0.f, by = 0.f, bz = 0.f, bw = 0.f;
    float cx = 0.f, cy = 0.f, cz = 0.f, cw = 0.f;
    float dx = 0.f, dy = 0.f, dz = 0.f, dw = 0.f;
    int e = ptr[node], e1 = pend[node];
    for (; e + 3 < e1; e += 4) {
        int s0 = srcs[e], s1 = srcs[e + 1], s2 = srcs[e + 2], s3 = srcs[e + 3];
        ushort4 v0 = G[s0 * 4 + q];
        ushort4 v1 = G[s1 * 4 + q];
        ushort4 v2 = G[s2 * 4 + q];
        ushort4 v3 = G[s3 * 4 + q];
        ax += bf2f(v0.x); ay += bf2f(v0.y); az += bf2f(v0.z); aw += bf2f(v0.w);
        bx += bf2f(v1.x); by += bf2f(v1.y); bz += bf2f(v1.z); bw += bf2f(v1.w);
        cx += bf2f(v2.x); cy += bf2f(v2.y); cz += bf2f(v2.z); cw += bf2f(v2.w);
        dx += bf2f(v3.x); dy += bf2f(v3.y); dz += bf2f(v3.z); dw += bf2f(v3.w);
    }
    for (; e < e1; ++e) {
        ushort4 v = G[srcs[e] * 4 + q];
        ax += bf2f(v.x); ay += bf2f(v.y); az += bf2f(v.z); aw += bf2f(v.w);
    }
    ax += bx + cx + dx;
    ay += by + cy + dy;
    az += bz + cz + dz;
    aw += bw + cw + dw;
    // per-lane partial y over this lane's 4 features, then 2-step butterfly
    const float* w0 = w2s + (4 * q + 0) * 41;
    const float* w1 = w2s + (4 * q + 1) * 41;
    const float* w2r = w2s + (4 * q + 2) * 41;
    const float* w3 = w2s + (4 * q + 3) * 41;
    float y[CC];
#pragma unroll
    for (int c = 0; c < CC; ++c)
        y[c] = fmaf(ax, w0[c], fmaf(ay, w1[c], fmaf(az, w2r[c], aw * w3[c])));
#pragma unroll
    for (int c = 0; c < CC; ++c) {
        y[c] += __shfl_xor(y[c], 1);
        y[c] += __shfl_xor(y[c], 2);
    }
    float di = dinv[node];
    float m = -3.0e38f;
#pragma unroll
    for (int c = 0; c < CC; ++c) {
        y[c] = fmaf(di, y[c], b2s[c]);
        m = fmaxf(m, y[c]);
    }
    float ssum = 0.f;
#pragma unroll
    for (int c = 0; c < CC; ++c) ssum += expf(y[c] - m);
    float l = logf(ssum) + m;
    // lane q writes classes [10q, 10q+10) — predicated static-index selection
    float ov[10];
#pragma unroll
    for (int c = 0; c < CC; ++c) {
        if ((c / 10) == q) ov[c % 10] = y[c] - l;
    }
    float2* o2 = reinterpret_cast<float2*>(out + (size_t)node * CC + 10 * q);
#pragma unroll
    for (int i = 0; i < 5; ++i) o2[i] = make_float2(ov[2 * i], ov[2 * i + 1]);
}

extern "C" void kernel_launch(void* const* d_in, const int* in_sizes, int n_in,
                              void* d_out, int out_size, void* d_ws, size_t ws_size,
                              hipStream_t stream) {
    const float* x  = (const float*)d_in[0];
    const int*   ei = (const int*)d_in[1];
    const float* W1 = (const float*)d_in[2];
    const float* b1 = (const float*)d_in[3];
    const float* W2 = (const float*)d_in[4];
    const float* b2 = (const float*)d_in[5];
    float* out = (float*)d_out;

    char* w = (char*)d_ws;
    auto alloc = [&](size_t bytes) {
        char* p = w;
        w += (bytes + 255) & ~(size_t)255;
        return p;
    };
    int*            head  = (int*)alloc((size_t)NB * 4);
    int*            ptr   = (int*)alloc((size_t)NN * 4);
    int*            pend  = (int*)alloc((size_t)NN * 4);
    float*          dinv  = (float*)alloc((size_t)NN * 4);
    unsigned*       pairs = (unsigned*)alloc((size_t)NB * CAP * 4);  // 16 MB
    int*            srcs  = (int*)alloc((size_t)NB * CAP * 4);       // 16 MB
    float*          g1f   = (float*)alloc((size_t)NN * HH * 4);      // 6.4 MB
    unsigned short* g1    = (unsigned short*)alloc((size_t)NN * HH * 2);
    unsigned short* g2h   = (unsigned short*)alloc((size_t)NN * HH * 2);

    hipMemsetAsync(head, 0, (size_t)NB * sizeof(int), stream);
    k_bin<<<TC, 256, 0, stream>>>(ei, head, pairs);
    k_buildgemm<<<NB + GB2, 256, 0, stream>>>(pairs, head, ptr, pend, dinv, srcs,
                                              x, W1, g1f);
    k_scale<<<GB, 256, 0, stream>>>(g1f, dinv, g1);
    int nt = NN * 4;
    k_agg1<<<(nt + 255) / 256, 256, 0, stream>>>(g1, ptr, pend, srcs, dinv, b1, g2h);
    k_agg2out<<<(nt + 255) / 256, 256, 0, stream>>>(g2h, ptr, pend, srcs, dinv,
                                                    W2, b2, out);
}

// Round 5
// 462.318 us; speedup vs baseline: 1.0625x; 1.0625x over previous
//
#include <hip/hip_runtime.h>

#define NN 100000
#define EE 3200000
#define FIN 512
#define HH 16
#define CC 40

#define SHIFT 9
#define BNODES 512                       // nodes per bucket
#define NB 196                           // ceil(NN/BNODES)
#define CAP 20480                        // per-bucket slot capacity (mean 16384, +32 sigma)
#define CH 2048                          // edges per binning chunk (8/thread in regs)
#define TC ((EE + CH - 1) / CH)          // 1563 chunks
#define GB ((NN * 4 + 255) / 256)        // 1563 blocks for quad-per-node kernels
#define GB2 ((NN + 63) / 64)             // 1563 gemm blocks (64 nodes x 4 k-quarters)

// bf16 helpers (manual RTNE; values here are finite and well-scaled)
__device__ __forceinline__ float bf2f(unsigned short u) {
    return __uint_as_float(((unsigned)u) << 16);
}
__device__ __forceinline__ unsigned short f2bf(float f) {
    unsigned b = __float_as_uint(f);
    return (unsigned short)((b + 0x7FFF + ((b >> 16) & 1)) >> 16);
}

// ---------------- bin edges into fixed-capacity buckets (packed u32) ----------
// Single pass over edge_index; 8 edges/thread held in REGISTERS (static-index
// unroll) between histogram and placement phases — no LDS stash, LDS = 2.4 KB.
// word = (dst_local << 17) | src   (src < 2^17, dst_local < 512)
__global__ void k_bin(const int* __restrict__ ei, int* __restrict__ head,
                      unsigned* __restrict__ pairs) {
    __shared__ int h[NB];
    __shared__ int gbase[NB];
    __shared__ int lhead[NB];
    __shared__ int is64_s;
    int t = threadIdx.x;
    // inline dtype detect: int64 layout => high words (odd int32 slots) all zero
    if (t < 64) {
        int nz = (ei[2 * t + 1] != 0) ? 1 : 0;
        unsigned long long m = __ballot(nz);
        if (t == 0) is64_s = (m == 0ULL) ? 1 : 0;
    }
    for (int i = t; i < NB; i += 256) { h[i] = 0; lhead[i] = 0; }
    __syncthreads();
    int is64 = is64_s;
    int e0 = blockIdx.x * CH;
    unsigned es[8], ed[8];
    // phase A: read edges ONCE into registers, histogram dst buckets
#pragma unroll
    for (int j = 0; j < 8; ++j) {
        int e = e0 + j * 256 + t;
        if (e < EE) {
            es[j] = (unsigned)(is64 ? ei[2 * e] : ei[e]);
            ed[j] = (unsigned)(is64 ? ei[2 * (EE + e)] : ei[EE + e]);
            atomicAdd(&h[ed[j] >> SHIFT], 1);
        }
    }
    __syncthreads();
    // one global reservation per (block,bucket): block-private contiguous runs
    for (int i = t; i < NB; i += 256)
        gbase[i] = h[i] ? atomicAdd(&head[i], h[i]) : 0;
    __syncthreads();
    // phase B: place from registers
#pragma unroll
    for (int j = 0; j < 8; ++j) {
        int e = e0 + j * 256 + t;
        if (e < EE) {
            int b = (int)(ed[j] >> SHIFT);
            int p = gbase[b] + atomicAdd(&lhead[b], 1);
            pairs[(size_t)b * CAP + p] = ((ed[j] & (BNODES - 1)) << 17) | es[j];
        }
    }
}

// 16 FMAs: one k-quad (4 k's x 4 features... actually 4 k's applied to 16 feats
// would be 64; here xv = 4 consecutive k values, wr = W1 row base, 16 features)
#define FMA_QUAD(xv, wr)                                                     \
    do {                                                                     \
        _Pragma("unroll") for (int f = 0; f < HH; ++f)                       \
            acc[f] = fmaf((xv).x, (wr)[f], acc[f]);                          \
        _Pragma("unroll") for (int f = 0; f < HH; ++f)                       \
            acc[f] = fmaf((xv).y, (wr)[HH + f], acc[f]);                     \
        _Pragma("unroll") for (int f = 0; f < HH; ++f)                       \
            acc[f] = fmaf((xv).z, (wr)[2 * HH + f], acc[f]);                 \
        _Pragma("unroll") for (int f = 0; f < HH; ++f)                       \
            acc[f] = fmaf((xv).w, (wr)[3 * HH + f], acc[f]);                 \
    } while (0)

// ------- fused: blocks [0,NB) build CSR; blocks [NB,NB+GB2) compute g1f -------
// R3 structure (scalar-W1, no LDS in hot loop) was latency-bound: VGPR=20 =>
// ONE x-load in flight, 32 serial ~900cyc HBM loads. R4's LDS staging regressed
// (barrier-coupled, 2-deep). Fix: 4-deep REGISTER prefetch pipeline, no
// barriers. FMA accumulation order identical to R3 => bit-identical output.
__global__ void __launch_bounds__(256) k_buildgemm(
        const unsigned* __restrict__ pairs, const int* __restrict__ head,
        int* __restrict__ ptr, int* __restrict__ pend,
        float* __restrict__ dinv, int* __restrict__ srcs,
        const float* __restrict__ x, const float* __restrict__ W1,
        float* __restrict__ g1f) {
    __shared__ float red[4][64][17];  // 17.4 KB; stride 17 -> conflict-free
    int t = threadIdx.x;
    if (blockIdx.x < NB) {
        // ---------------- build path (LDS overlay on red) ----------------
        int* h   = (int*)red;               // [BNODES]
        int* lex = (int*)red + BNODES;      // [BNODES]
        int* wsm = (int*)red + 2 * BNODES;  // [4]
        int b = blockIdx.x, lane = t & 63, wid = t >> 6;
        int node0 = b << SHIFT;
        int p0 = b * CAP;
        int cnt = head[b];
        for (int i = t; i < BNODES; i += 256) h[i] = 0;
        __syncthreads();
        for (int p = t; p < cnt; p += 256) atomicAdd(&h[pairs[p0 + p] >> 17], 1);
        __syncthreads();
        // exclusive scan over 512 counts: thread t owns elements 2t, 2t+1
        int a0 = h[2 * t], a1 = h[2 * t + 1];
        int s = a0 + a1;
        int v = s;
#pragma unroll
        for (int off = 1; off < 64; off <<= 1) {
            int u = __shfl_up(v, off);
            if (lane >= off) v += u;
        }
        if (lane == 63) wsm[wid] = v;
        __syncthreads();
        int add = 0;
        for (int w = 0; w < wid; ++w) add += wsm[w];
        int incl = v + add;
        int e0 = incl - s;
        lex[2 * t] = e0;
        lex[2 * t + 1] = e0 + a0;
        __syncthreads();
        for (int i = t; i < BNODES; i += 256) {
            int n = node0 + i;
            if (n < NN) {
                int st = p0 + lex[i];
                ptr[n] = st;
                pend[n] = st + h[i];
                dinv[n] = rsqrtf((float)(h[i] + 1));  // +1 self loop
            }
        }
        __syncthreads();
        for (int p = t; p < cnt; p += 256) {
            unsigned w = pairs[p0 + p];
            int pos = p0 + atomicAdd(&lex[w >> 17], 1);
            srcs[pos] = (int)(w & 0x1FFFF);
        }
    } else {
        // ------------- gemm path: g1f = x @ W1 (f32, unscaled) -----------
        int kq = __builtin_amdgcn_readfirstlane(t >> 6);  // wave-uniform SGPR
        int n = t & 63;
        int base = (blockIdx.x - NB) * 64;
        int nc = min(base + n, NN - 1);  // clamp (selects, not branches)
        const float4* xr = reinterpret_cast<const float4*>(
            x + (size_t)nc * FIN + kq * 128);
        const float* wb = W1 + kq * 128 * HH;  // uniform base -> s_load
        float acc[HH];
#pragma unroll
        for (int f = 0; f < HH; ++f) acc[f] = 0.f;
        // 4-deep register prefetch pipeline: always >=4 independent HBM loads
        // in flight per thread (R3's compiler schedule had only 1).
        float4 p0 = xr[0], p1 = xr[1], p2 = xr[2], p3 = xr[3];
#pragma unroll
        for (int i = 0; i < 32; i += 4) {
            float4 q0, q1, q2, q3;
            if (i + 4 < 32) {
                q0 = xr[i + 4];
                q1 = xr[i + 5];
                q2 = xr[i + 6];
                q3 = xr[i + 7];
            } else {
                q0 = p0; q1 = p1; q2 = p2; q3 = p3;  // dead, folds away
            }
            FMA_QUAD(p0, wb + (i + 0) * 4 * HH);
            FMA_QUAD(p1, wb + (i + 1) * 4 * HH);
            FMA_QUAD(p2, wb + (i + 2) * 4 * HH);
            FMA_QUAD(p3, wb + (i + 3) * 4 * HH);
            p0 = q0; p1 = q1; p2 = q2; p3 = q3;
        }
#pragma unroll
        for (int f = 0; f < HH; ++f) red[kq][n][f] = acc[f];
        __syncthreads();
        // reduce 4 k-quarters; thread t: node lane n=t&63, feature quad g=t>>6
        int g = t >> 6;
        int f0 = g * 4;
        float r0 = red[0][n][f0]     + red[1][n][f0]     + red[2][n][f0]     + red[3][n][f0];
        float r1 = red[0][n][f0 + 1] + red[1][n][f0 + 1] + red[2][n][f0 + 1] + red[3][n][f0 + 1];
        float r2 = red[0][n][f0 + 2] + red[1][n][f0 + 2] + red[2][n][f0 + 2] + red[3][n][f0 + 2];
        float r3 = red[0][n][f0 + 3] + red[1][n][f0 + 3] + red[2][n][f0 + 3] + red[3][n][f0 + 3];
        int node = base + n;
        if (node < NN)
            reinterpret_cast<float4*>(g1f)[node * 4 + g] =
                make_float4(r0, r1, r2, r3);
    }
}

// ---- tiny pass: g1 = bf16(g1f * dinv) — single bf16 rounding, same as R1 -----
__global__ void k_scale(const float* __restrict__ g1f, const float* __restrict__ dinv,
                        unsigned short* __restrict__ g1) {
    int gt = blockIdx.x * 256 + threadIdx.x;
    int node = gt >> 2, q = gt & 3;
    if (node >= NN) return;
    float di = dinv[node];
    float4 v = reinterpret_cast<const float4*>(g1f)[node * 4 + q];
    ushort4 o;
    o.x = f2bf(v.x * di);
    o.y = f2bf(v.y * di);
    o.z = f2bf(v.z * di);
    o.w = f2bf(v.w * di);
    reinterpret_cast<ushort4*>(g1)[node * 4 + q] = o;
}

// ---------------- agg1: CSR gather (bf16), relu epilogue -> g2h (bf16) --------
__global__ void k_agg1(const unsigned short* __restrict__ g1, const int* __restrict__ ptr,
                       const int* __restrict__ pend, const int* __restrict__ srcs,
                       const float* __restrict__ dinv, const float* __restrict__ b1,
                       unsigned short* __restrict__ g2h) {
    int gt = blockIdx.x * blockDim.x + threadIdx.x;
    int node = gt >> 2, q = gt & 3;
    if (node >= NN) return;
    const ushort4* G = reinterpret_cast<const ushort4*>(g1);
    ushort4 sv = G[node * 4 + q];  // self term
    float ax = bf2f(sv.x), ay = bf2f(sv.y), az = bf2f(sv.z), aw = bf2f(sv.w);
    float bx = 0.f, by = 0.f, bz = 0.f, bw = 0.f;
    float cx = 0.f, cy = 0.f, cz = 0.f, cw = 0.f;
    float dx = 0.f, dy = 0.f, dz = 0.f, dw = 0.f;
    int e = ptr[node], e1 = pend[node];
    for (; e + 3 < e1; e += 4) {
        int s0 = srcs[e], s1 = srcs[e + 1], s2 = srcs[e + 2], s3 = srcs[e + 3];
        ushort4 v0 = G[s0 * 4 + q];
        ushort4 v1 = G[s1 * 4 + q];
        ushort4 v2 = G[s2 * 4 + q];
        ushort4 v3 = G[s3 * 4 + q];
        ax += bf2f(v0.x); ay += bf2f(v0.y); az += bf2f(v0.z); aw += bf2f(v0.w);
        bx += bf2f(v1.x); by += bf2f(v1.y); bz += bf2f(v1.z); bw += bf2f(v1.w);
        cx += bf2f(v2.x); cy += bf2f(v2.y); cz += bf2f(v2.z); cw += bf2f(v2.w);
        dx += bf2f(v3.x); dy += bf2f(v3.y); dz += bf2f(v3.z); dw += bf2f(v3.w);
    }
    for (; e < e1; ++e) {
        ushort4 v = G[srcs[e] * 4 + q];
        ax += bf2f(v.x); ay += bf2f(v.y); az += bf2f(v.z); aw += bf2f(v.w);
    }
    ax += bx + cx + dx;
    ay += by + cy + dy;
    az += bz + cz + dz;
    aw += bw + cw + dw;
    float di = dinv[node];
    const float4 bb = reinterpret_cast<const float4*>(b1)[q];
    ushort4 r;
    r.x = f2bf(fmaxf(fmaf(di, ax, bb.x), 0.f) * di);
    r.y = f2bf(fmaxf(fmaf(di, ay, bb.y), 0.f) * di);
    r.z = f2bf(fmaxf(fmaf(di, az, bb.z), 0.f) * di);
    r.w = f2bf(fmaxf(fmaf(di, aw, bb.w), 0.f) * di);
    reinterpret_cast<ushort4*>(g2h)[node * 4 + q] = r;
}

// ------ fused agg2 + out: CSR gather -> W2 partials -> quad butterfly ---------
// ------   -> bias/scale -> log_softmax -> direct write of final output --------
__global__ void __launch_bounds__(256) k_agg2out(
        const unsigned short* __restrict__ g2h, const int* __restrict__ ptr,
        const int* __restrict__ pend, const int* __restrict__ srcs,
        const float* __restrict__ dinv, const float* __restrict__ W2,
        const float* __restrict__ b2, float* __restrict__ out) {
    __shared__ float w2s[HH * 41];  // stride 41 breaks 4-way bank conflict (160%32==0)
    __shared__ float b2s[CC];
    int t = threadIdx.x;
    for (int i = t; i < HH * CC; i += 256) w2s[(i / CC) * 41 + (i % CC)] = W2[i];
    if (t < CC) b2s[t] = b2[t];
    __syncthreads();
    int gt = blockIdx.x * blockDim.x + t;
    int node = gt >> 2, q = gt & 3;
    if (node >= NN) return;
    const ushort4* G = reinterpret_cast<const ushort4*>(g2h);
    ushort4 sv = G[node * 4 + q];  // self term
    float ax = bf2f(sv.x), ay = bf2f(sv.y), az = bf2f(sv.z), aw = bf2f(sv.w);
    float bx = 0.f, by = 0.f, bz = 0.f, bw = 0.f;
    float cx = 0.f, cy = 0.f, cz = 0.f, cw = 0.f;
    float dx = 0.f, dy = 0.f, dz = 0.f, dw = 0.f;
    int e = ptr[node], e1 = pend[node];
    for (; e + 3 < e1; e += 4) {
        int s0 = srcs[e], s1 = srcs[e + 1], s2 = srcs[e + 2], s3 = srcs[e + 3];
        ushort4 v0 = G[s0 * 4 + q];
        ushort4 v1 = G[s1 * 4 + q];
        ushort4 v2 = G[s2 * 4 + q];
        ushort4 v3 = G[s3 * 4 + q];
        ax += bf2f(v0.x); ay += bf2f(v0.y); az += bf2f(v0.z); aw += bf2f(v0.w);
        bx += bf2f(v1.x); by += bf2f(v1.y); bz += bf2f(v1.z); bw += bf2f(v1.w);
        cx += bf2f(v2.x); cy += bf2f(v2.y); cz += bf2f(v2.z); cw += bf2f(v2.w);
        dx += bf2f(v3.x); dy += bf2f(v3.y); dz += bf2f(v3.z); dw += bf2f(v3.w);
    }
    for (; e < e1; ++e) {
        ushort4 v = G[srcs[e] * 4 + q];
        ax += bf2f(v.x); ay += bf2f(v.y); az += bf2f(v.z); aw += bf2f(v.w);
    }
    ax += bx + cx + dx;
    ay += by + cy + dy;
    az += bz + cz + dz;
    aw += bw + cw + dw;
    // per-lane partial y over this lane's 4 features, then 2-step butterfly
    const float* w0 = w2s + (4 * q + 0) * 41;
    const float* w1 = w2s + (4 * q + 1) * 41;
    const float* w2r = w2s + (4 * q + 2) * 41;
    const float* w3 = w2s + (4 * q + 3) * 41;
    float y[CC];
#pragma unroll
    for (int c = 0; c < CC; ++c)
        y[c] = fmaf(ax, w0[c], fmaf(ay, w1[c], fmaf(az, w2r[c], aw * w3[c])));
#pragma unroll
    for (int c = 0; c < CC; ++c) {
        y[c] += __shfl_xor(y[c], 1);
        y[c] += __shfl_xor(y[c], 2);
    }
    float di = dinv[node];
    float m = -3.0e38f;
#pragma unroll
    for (int c = 0; c < CC; ++c) {
        y[c] = fmaf(di, y[c], b2s[c]);
        m = fmaxf(m, y[c]);
    }
    float ssum = 0.f;
#pragma unroll
    for (int c = 0; c < CC; ++c) ssum += expf(y[c] - m);
    float l = logf(ssum) + m;
    // lane q writes classes [10q, 10q+10) — predicated static-index selection
    float ov[10];
#pragma unroll
    for (int c = 0; c < CC; ++c) {
        if ((c / 10) == q) ov[c % 10] = y[c] - l;
    }
    float2* o2 = reinterpret_cast<float2*>(out + (size_t)node * CC + 10 * q);
#pragma unroll
    for (int i = 0; i < 5; ++i) o2[i] = make_float2(ov[2 * i], ov[2 * i + 1]);
}

extern "C" void kernel_launch(void* const* d_in, const int* in_sizes, int n_in,
                              void* d_out, int out_size, void* d_ws, size_t ws_size,
                              hipStream_t stream) {
    const float* x  = (const float*)d_in[0];
    const int*   ei = (const int*)d_in[1];
    const float* W1 = (const float*)d_in[2];
    const float* b1 = (const float*)d_in[3];
    const float* W2 = (const float*)d_in[4];
    const float* b2 = (const float*)d_in[5];
    float* out = (float*)d_out;

    char* w = (char*)d_ws;
    auto alloc = [&](size_t bytes) {
        char* p = w;
        w += (bytes + 255) & ~(size_t)255;
        return p;
    };
    int*            head  = (int*)alloc((size_t)NB * 4);
    int*            ptr   = (int*)alloc((size_t)NN * 4);
    int*            pend  = (int*)alloc((size_t)NN * 4);
    float*          dinv  = (float*)alloc((size_t)NN * 4);
    unsigned*       pairs = (unsigned*)alloc((size_t)NB * CAP * 4);  // 16 MB
    int*            srcs  = (int*)alloc((size_t)NB * CAP * 4);       // 16 MB
    float*          g1f   = (float*)alloc((size_t)NN * HH * 4);      // 6.4 MB
    unsigned short* g1    = (unsigned short*)alloc((size_t)NN * HH * 2);
    unsigned short* g2h   = (unsigned short*)alloc((size_t)NN * HH * 2);

    hipMemsetAsync(head, 0, (size_t)NB * sizeof(int), stream);
    k_bin<<<TC, 256, 0, stream>>>(ei, head, pairs);
    k_buildgemm<<<NB + GB2, 256, 0, stream>>>(pairs, head, ptr, pend, dinv, srcs,
                                              x, W1, g1f);
    k_scale<<<GB, 256, 0, stream>>>(g1f, dinv, g1);
    int nt = NN * 4;
    k_agg1<<<(nt + 255) / 256, 256, 0, stream>>>(g1, ptr, pend, srcs, dinv, b1, g2h);
    k_agg2out<<<(nt + 255) / 256, 256, 0, stream>>>(g2h, ptr, pend, srcs, dinv,
                                                    W2, b2, out);
}